// Round 1
// baseline (539.757 us; speedup 1.0000x reference)
//
#include <hip/hip_runtime.h>

#define NPTS   65536
#define DIM    128
#define KCODES 1024
#define BM     128
#define BN     128
#define TM     8
#define TN     8

// ---------------- Kernel 0: halfnorm[c] = 0.5 * ||embed[c]||^2 ----------------
__global__ __launch_bounds__(256)
void halfnorm_kernel(const float* __restrict__ embed, float* __restrict__ hn)
{
    const int w    = (blockIdx.x * blockDim.x + threadIdx.x) >> 6;  // one wave per code
    const int lane = threadIdx.x & 63;
    if (w < KCODES) {
        float v0 = embed[(long)w * DIM + lane];
        float v1 = embed[(long)w * DIM + 64 + lane];
        float s  = v0 * v0 + v1 * v1;
        #pragma unroll
        for (int off = 32; off > 0; off >>= 1) s += __shfl_xor(s, off);
        if (lane == 0) hn[w] = 0.5f * s;
    }
}

// ---------------- Kernel 1: argmin over codes + quantize gather ----------------
// score = dot(x, e) - 0.5*||e||^2 ; argmax(score) == argmin(-2 dot + ||e||^2)
__global__ __launch_bounds__(256, 1)
void argmin_kernel(const float* __restrict__ x, const float* __restrict__ embed,
                   const float* __restrict__ halfnorm, int* __restrict__ ind,
                   float* __restrict__ quant)
{
    __shared__ float xs[DIM][BM];   // 64 KB, transposed x tile
    __shared__ float es[DIM][BN];   // 64 KB, transposed code tile (reused as scratch at end)

    const int t     = threadIdx.x;
    const int row   = t >> 4;    // 0..15
    const int col   = t & 15;    // 0..15
    const int block = blockIdx.x;
    const long xbase = (long)block * BM * DIM;

    // stage x tile transposed: thread -> (p = t&127, d4 chunks)
    {
        const int p = t & 127;
        #pragma unroll
        for (int d4 = (t >> 7); d4 < 32; d4 += 2) {
            float4 v = *reinterpret_cast<const float4*>(x + xbase + (long)p * DIM + d4 * 4);
            xs[d4 * 4 + 0][p] = v.x; xs[d4 * 4 + 1][p] = v.y;
            xs[d4 * 4 + 2][p] = v.z; xs[d4 * 4 + 3][p] = v.w;
        }
    }

    float bestv[TM];
    int   besti[TM];
    #pragma unroll
    for (int i = 0; i < TM; ++i) { bestv[i] = -1e30f; besti[i] = 0; }

    float acc[TM][TN];

    for (int tile = 0; tile < KCODES / BN; ++tile) {
        __syncthreads();   // protect previous tile's readers (and xs staging on tile 0)
        {
            const int  c     = t & 127;
            const long ebase = (long)(tile * BN) * DIM;
            #pragma unroll
            for (int d4 = (t >> 7); d4 < 32; d4 += 2) {
                float4 v = *reinterpret_cast<const float4*>(embed + ebase + (long)c * DIM + d4 * 4);
                es[d4 * 4 + 0][c] = v.x; es[d4 * 4 + 1][c] = v.y;
                es[d4 * 4 + 2][c] = v.z; es[d4 * 4 + 3][c] = v.w;
            }
        }
        __syncthreads();

        #pragma unroll
        for (int i = 0; i < TM; ++i)
            #pragma unroll
            for (int j = 0; j < TN; ++j) acc[i][j] = 0.f;

        #pragma unroll 4
        for (int d = 0; d < DIM; ++d) {
            float4 a0 = *reinterpret_cast<const float4*>(&xs[d][row * 8]);
            float4 a1 = *reinterpret_cast<const float4*>(&xs[d][row * 8 + 4]);
            float4 b0 = *reinterpret_cast<const float4*>(&es[d][col * 4]);        // codes col*4..+3
            float4 b1 = *reinterpret_cast<const float4*>(&es[d][64 + col * 4]);   // codes 64+col*4..+3
            float a[8] = {a0.x, a0.y, a0.z, a0.w, a1.x, a1.y, a1.z, a1.w};
            float b[8] = {b0.x, b0.y, b0.z, b0.w, b1.x, b1.y, b1.z, b1.w};
            #pragma unroll
            for (int i = 0; i < TM; ++i)
                #pragma unroll
                for (int j = 0; j < TN; ++j)
                    acc[i][j] = fmaf(a[i], b[j], acc[i][j]);
        }

        // per-tile argmax update (codes visited in ascending index order per thread)
        float hn[TN];
        #pragma unroll
        for (int j = 0; j < TN; ++j) {
            int c = tile * BN + (j < 4 ? col * 4 + j : 64 + col * 4 + (j - 4));
            hn[j] = halfnorm[c];
        }
        #pragma unroll
        for (int i = 0; i < TM; ++i) {
            #pragma unroll
            for (int j = 0; j < TN; ++j) {
                int   c = tile * BN + (j < 4 ? col * 4 + j : 64 + col * 4 + (j - 4));
                float s = acc[i][j] - hn[j];
                if (s > bestv[i]) { bestv[i] = s; besti[i] = c; }   // strict > keeps smallest idx
            }
        }
    }

    // cross-column reduction via scratch overlaid on es (compute done)
    __syncthreads();
    float (*redv)[16] = reinterpret_cast<float(*)[16]>(&es[0][0]);          // 8 KB
    int   (*redi)[16] = reinterpret_cast<int  (*)[16]>(&es[16][0]);         // 8 KB
    int*   bidx       = reinterpret_cast<int*>(&es[32][0]);                 // 512 B

    #pragma unroll
    for (int i = 0; i < TM; ++i) {
        redv[row * 8 + i][col] = bestv[i];
        redi[row * 8 + i][col] = besti[i];
    }
    __syncthreads();
    if (t < BM) {
        float bv = redv[t][0];
        int   bi = redi[t][0];
        #pragma unroll
        for (int cc = 1; cc < 16; ++cc) {
            float v  = redv[t][cc];
            int   ci = redi[t][cc];
            if (v > bv || (v == bv && ci < bi)) { bv = v; bi = ci; }
        }
        ind[block * BM + t] = bi;
        bidx[t] = bi;
    }
    __syncthreads();

    // quantize: copy embed[best] rows to out (2 threads per point, 64 dims each)
    {
        const int p = t >> 1, h = t & 1;
        const int c = bidx[p];
        const float* src = embed + (long)c * DIM + h * 64;
        float*       dst = quant + xbase + (long)p * DIM + h * 64;
        #pragma unroll
        for (int k = 0; k < 16; ++k)
            reinterpret_cast<float4*>(dst)[k] = reinterpret_cast<const float4*>(src)[k];
    }
}

// ---------------- Kernel 2: code-centric segment sums + EMA epilogue ----------------
#define CPB 4
__global__ __launch_bounds__(256)
void segsum_kernel(const float* __restrict__ x, const int* __restrict__ ind,
                   const float* __restrict__ ema_embed, const float* __restrict__ ema_num,
                   float* __restrict__ embed_new, float* __restrict__ ema_embed_new,
                   float* __restrict__ ema_num_new)
{
    __shared__ float wacc[4][CPB][DIM];   // 8 KB
    __shared__ int   wcnt[4][CPB];

    const int t    = threadIdx.x;
    const int w    = t >> 6;
    const int lane = t & 63;
    const int blk  = blockIdx.x;

    for (int i = t; i < 4 * CPB * DIM; i += 256) (&wacc[0][0][0])[i] = 0.f;
    __syncthreads();

    int cnt[CPB] = {0, 0, 0, 0};
    for (int k = 0; k < NPTS / 256; ++k) {
        const int i = k * 256 + t;
        const int v = ind[i];
        unsigned long long any = __ballot((v >> 2) == blk);
        if (any) {
            #pragma unroll
            for (int cc = 0; cc < CPB; ++cc) {
                unsigned long long m = __ballot(v == blk * CPB + cc);
                cnt[cc] += (int)__popcll(m);
                while (m) {
                    int l = __ffsll((unsigned long long)m) - 1;
                    m &= m - 1;
                    long p = (long)k * 256 + w * 64 + l;
                    wacc[w][cc][lane]      += x[p * DIM + lane];
                    wacc[w][cc][lane + 64] += x[p * DIM + 64 + lane];
                }
            }
        }
    }
    if (lane == 0) {
        #pragma unroll
        for (int cc = 0; cc < CPB; ++cc) wcnt[w][cc] = cnt[cc];
    }
    __syncthreads();

    if (t < DIM) {
        #pragma unroll
        for (int cc = 0; cc < CPB; ++cc) {
            const int c = blk * CPB + cc;
            float n  = (float)(wcnt[0][cc] + wcnt[1][cc] + wcnt[2][cc] + wcnt[3][cc]);
            float en = ema_num[c] * 0.8f + 0.2f * n;
            float s  = wacc[0][cc][t] + wacc[1][cc][t] + wacc[2][cc][t] + wacc[3][cc][t];
            float ee = ema_embed[(long)c * DIM + t] * 0.8f + 0.2f * s;
            ema_embed_new[(long)c * DIM + t] = ee;
            embed_new[(long)c * DIM + t]     = ee / en;
            if (t < CPB && cc == 0) {
                const int c2 = blk * CPB + t;
                float n2 = (float)(wcnt[0][t] + wcnt[1][t] + wcnt[2][t] + wcnt[3][t]);
                ema_num_new[c2] = ema_num[c2] * 0.8f + 0.2f * n2;
            }
        }
    }
}

extern "C" void kernel_launch(void* const* d_in, const int* in_sizes, int n_in,
                              void* d_out, int out_size, void* d_ws, size_t ws_size,
                              hipStream_t stream)
{
    const float* x         = (const float*)d_in[0];
    const float* embed     = (const float*)d_in[1];
    const float* ema_embed = (const float*)d_in[2];
    const float* ema_num   = (const float*)d_in[3];

    float* out0 = (float*)d_out;            // quantize      (16*4096*128)
    float* out1 = out0 + 8388608;           // embed_new     (1024*128)
    float* out2 = out1 + 131072;            // ema_embed_new (1024*128)
    float* out3 = out2 + 131072;            // ema_num_new   (1024)

    float* hn  = (float*)d_ws;                       // 1024 floats
    int*   ind = (int*)((char*)d_ws + 4096);         // 65536 ints

    halfnorm_kernel<<<256, 256, 0, stream>>>(embed, hn);
    argmin_kernel<<<NPTS / BM, 256, 0, stream>>>(x, embed, hn, ind, out0);
    segsum_kernel<<<KCODES / CPB, 256, 0, stream>>>(x, ind, ema_embed, ema_num,
                                                    out1, out2, out3);
}

// Round 2
// 500.182 us; speedup vs baseline: 1.0791x; 1.0791x over previous
//
#include <hip/hip_runtime.h>

#define NPTS   65536
#define DIM    128
#define KCODES 1024
#define BM     128
#define BN     128
#define NTHR   512
#define TM     8     // points per thread
#define TN     4     // codes per thread

// ---------------- Kernel 0: halfnorm[c] = 0.5 * ||embed[c]||^2 ----------------
__global__ __launch_bounds__(256)
void halfnorm_kernel(const float* __restrict__ embed, float* __restrict__ hn)
{
    const int w    = (blockIdx.x * blockDim.x + threadIdx.x) >> 6;  // one wave per code
    const int lane = threadIdx.x & 63;
    if (w < KCODES) {
        float v0 = embed[(long)w * DIM + lane];
        float v1 = embed[(long)w * DIM + 64 + lane];
        float s  = v0 * v0 + v1 * v1;
        #pragma unroll
        for (int off = 32; off > 0; off >>= 1) s += __shfl_xor(s, off);
        if (lane == 0) hn[w] = 0.5f * s;
    }
}

// ---------------- Kernel 1: argmin over codes + quantize gather ----------------
// score = dot(x, e) - 0.5*||e||^2 ; argmax(score) == argmin(-2 dot + ||e||^2)
__global__ __launch_bounds__(NTHR, 2)
void argmin_kernel(const float* __restrict__ x, const float* __restrict__ embed,
                   const float* __restrict__ halfnorm, int* __restrict__ ind,
                   float* __restrict__ quant)
{
    __shared__ float xs[DIM][BM];   // 64 KB, transposed x tile
    __shared__ float es[DIM][BN];   // 64 KB, transposed code tile (reused as scratch at end)

    const int t     = threadIdx.x;
    const int row   = t >> 5;    // 0..15 -> points row*8..row*8+7
    const int col   = t & 31;    // 0..31 -> codes col*4..col*4+3
    const int block = blockIdx.x;
    const long xbase = (long)block * BM * DIM;

    // stage x tile transposed
    {
        const int p = t & 127;
        #pragma unroll
        for (int d4 = (t >> 7); d4 < 32; d4 += 4) {
            float4 v = *reinterpret_cast<const float4*>(x + xbase + (long)p * DIM + d4 * 4);
            xs[d4 * 4 + 0][p] = v.x; xs[d4 * 4 + 1][p] = v.y;
            xs[d4 * 4 + 2][p] = v.z; xs[d4 * 4 + 3][p] = v.w;
        }
    }

    float bestv[TM];
    int   besti[TM];
    #pragma unroll
    for (int i = 0; i < TM; ++i) { bestv[i] = -1e30f; besti[i] = 0; }

    float acc[TM][TN];

    for (int tile = 0; tile < KCODES / BN; ++tile) {
        __syncthreads();   // protect previous tile's readers (and xs staging on tile 0)
        {
            const int  c     = t & 127;
            const long ebase = (long)(tile * BN) * DIM;
            #pragma unroll
            for (int d4 = (t >> 7); d4 < 32; d4 += 4) {
                float4 v = *reinterpret_cast<const float4*>(embed + ebase + (long)c * DIM + d4 * 4);
                es[d4 * 4 + 0][c] = v.x; es[d4 * 4 + 1][c] = v.y;
                es[d4 * 4 + 2][c] = v.z; es[d4 * 4 + 3][c] = v.w;
            }
        }
        __syncthreads();

        #pragma unroll
        for (int i = 0; i < TM; ++i)
            #pragma unroll
            for (int j = 0; j < TN; ++j) acc[i][j] = 0.f;

        #pragma unroll 4
        for (int d = 0; d < DIM; ++d) {
            float4 a0 = *reinterpret_cast<const float4*>(&xs[d][row * 8]);
            float4 a1 = *reinterpret_cast<const float4*>(&xs[d][row * 8 + 4]);
            float4 b0 = *reinterpret_cast<const float4*>(&es[d][col * 4]);
            float a[8] = {a0.x, a0.y, a0.z, a0.w, a1.x, a1.y, a1.z, a1.w};
            float b[4] = {b0.x, b0.y, b0.z, b0.w};
            #pragma unroll
            for (int i = 0; i < TM; ++i)
                #pragma unroll
                for (int j = 0; j < TN; ++j)
                    acc[i][j] = fmaf(a[i], b[j], acc[i][j]);
        }

        // per-tile argmax update (codes visited in ascending index order per thread)
        float hn[TN];
        #pragma unroll
        for (int j = 0; j < TN; ++j) hn[j] = halfnorm[tile * BN + col * 4 + j];
        #pragma unroll
        for (int i = 0; i < TM; ++i) {
            #pragma unroll
            for (int j = 0; j < TN; ++j) {
                int   c = tile * BN + col * 4 + j;
                float s = acc[i][j] - hn[j];
                if (s > bestv[i]) { bestv[i] = s; besti[i] = c; }   // strict > keeps smallest idx
            }
        }
    }

    // cross-column reduction via scratch overlaid on es (compute done)
    __syncthreads();
    float (*redv)[32] = reinterpret_cast<float(*)[32]>(&es[0][0]);          // 16 KB
    int   (*redi)[32] = reinterpret_cast<int  (*)[32]>(&es[32][0]);         // 16 KB
    int*   bidx       = reinterpret_cast<int*>(&es[64][0]);                 // 512 B

    #pragma unroll
    for (int i = 0; i < TM; ++i) {
        redv[row * 8 + i][col] = bestv[i];
        redi[row * 8 + i][col] = besti[i];
    }
    __syncthreads();
    if (t < BM) {
        float bv = redv[t][0];
        int   bi = redi[t][0];
        #pragma unroll
        for (int cc = 1; cc < 32; ++cc) {
            float v  = redv[t][cc];
            int   ci = redi[t][cc];
            if (v > bv || (v == bv && ci < bi)) { bv = v; bi = ci; }
        }
        ind[block * BM + t] = bi;
        bidx[t] = bi;
    }
    __syncthreads();

    // quantize: lane-contiguous copy — each store instr writes 1 KB contiguous.
    // idx enumerates the block's 4096 float4s; point = idx>>5, q = idx&31.
    {
        float4*       dst = reinterpret_cast<float4*>(quant + xbase);
        #pragma unroll
        for (int k = 0; k < 8; ++k) {
            const int idx = k * NTHR + t;
            const int p   = idx >> 5;
            const int q   = idx & 31;
            const int c   = bidx[p];
            dst[idx] = reinterpret_cast<const float4*>(embed + (long)c * DIM)[q];
        }
    }
}

// ---------------- Kernel 2: code-centric segment sums + EMA epilogue ----------------
#define CPB 4
__global__ __launch_bounds__(256)
void segsum_kernel(const float* __restrict__ x, const int* __restrict__ ind,
                   const float* __restrict__ ema_embed, const float* __restrict__ ema_num,
                   float* __restrict__ embed_new, float* __restrict__ ema_embed_new,
                   float* __restrict__ ema_num_new)
{
    __shared__ float wacc[4][CPB][DIM];   // 8 KB
    __shared__ int   wcnt[4][CPB];

    const int t    = threadIdx.x;
    const int w    = t >> 6;
    const int lane = t & 63;
    const int blk  = blockIdx.x;

    for (int i = t; i < 4 * CPB * DIM; i += 256) (&wacc[0][0][0])[i] = 0.f;
    __syncthreads();

    int cnt[CPB] = {0, 0, 0, 0};
    for (int k = 0; k < NPTS / 256; ++k) {
        const int i = k * 256 + t;
        const int v = ind[i];
        unsigned long long any = __ballot((v >> 2) == blk);
        if (any) {
            #pragma unroll
            for (int cc = 0; cc < CPB; ++cc) {
                unsigned long long m = __ballot(v == blk * CPB + cc);
                cnt[cc] += (int)__popcll(m);
                while (m) {
                    int l = __ffsll((unsigned long long)m) - 1;
                    m &= m - 1;
                    long p = (long)k * 256 + w * 64 + l;
                    wacc[w][cc][lane]      += x[p * DIM + lane];
                    wacc[w][cc][lane + 64] += x[p * DIM + 64 + lane];
                }
            }
        }
    }
    if (lane == 0) {
        #pragma unroll
        for (int cc = 0; cc < CPB; ++cc) wcnt[w][cc] = cnt[cc];
    }
    __syncthreads();

    if (t < DIM) {
        #pragma unroll
        for (int cc = 0; cc < CPB; ++cc) {
            const int c = blk * CPB + cc;
            float n  = (float)(wcnt[0][cc] + wcnt[1][cc] + wcnt[2][cc] + wcnt[3][cc]);
            float en = ema_num[c] * 0.8f + 0.2f * n;
            float s  = wacc[0][cc][t] + wacc[1][cc][t] + wacc[2][cc][t] + wacc[3][cc][t];
            float ee = ema_embed[(long)c * DIM + t] * 0.8f + 0.2f * s;
            ema_embed_new[(long)c * DIM + t] = ee;
            embed_new[(long)c * DIM + t]     = ee / en;
            if (t < CPB && cc == 0) {
                const int c2 = blk * CPB + t;
                float n2 = (float)(wcnt[0][t] + wcnt[1][t] + wcnt[2][t] + wcnt[3][t]);
                ema_num_new[c2] = ema_num[c2] * 0.8f + 0.2f * n2;
            }
        }
    }
}

extern "C" void kernel_launch(void* const* d_in, const int* in_sizes, int n_in,
                              void* d_out, int out_size, void* d_ws, size_t ws_size,
                              hipStream_t stream)
{
    const float* x         = (const float*)d_in[0];
    const float* embed     = (const float*)d_in[1];
    const float* ema_embed = (const float*)d_in[2];
    const float* ema_num   = (const float*)d_in[3];

    float* out0 = (float*)d_out;            // quantize      (16*4096*128)
    float* out1 = out0 + 8388608;           // embed_new     (1024*128)
    float* out2 = out1 + 131072;            // ema_embed_new (1024*128)
    float* out3 = out2 + 131072;            // ema_num_new   (1024)

    float* hn  = (float*)d_ws;                       // 1024 floats
    int*   ind = (int*)((char*)d_ws + 4096);         // 65536 ints

    halfnorm_kernel<<<256, 256, 0, stream>>>(embed, hn);
    argmin_kernel<<<NPTS / BM, NTHR, 0, stream>>>(x, embed, hn, ind, out0);
    segsum_kernel<<<KCODES / CPB, 256, 0, stream>>>(x, ind, ema_embed, ema_num,
                                                    out1, out2, out3);
}

// Round 3
// 199.345 us; speedup vs baseline: 2.7077x; 2.5091x over previous
//
#include <hip/hip_runtime.h>

#define NPTS   65536
#define DIM    128
#define KCODES 1024
#define BM     256      // points per argmin block
#define TILE_C 128      // codes staged per LDS tile
#define NTHR   512

typedef short bf16x8 __attribute__((ext_vector_type(8)));
typedef float f32x4  __attribute__((ext_vector_type(4)));

__device__ __forceinline__ short f2bf(float f) {
    unsigned u = __builtin_bit_cast(unsigned, f);
    u = (u + 0x7fffu + ((u >> 16) & 1u)) >> 16;   // RNE
    return (short)u;
}
__device__ __forceinline__ float bf2f(short s) {
    unsigned u = ((unsigned)(unsigned short)s) << 16;
    return __builtin_bit_cast(float, u);
}

// ---------------- Kernel 0: halfnorm[c] = 0.5 * ||embed[c]||^2 (exact fp32) ----
__global__ __launch_bounds__(256)
void halfnorm_kernel(const float* __restrict__ embed, float* __restrict__ hn)
{
    const int w    = (blockIdx.x * blockDim.x + threadIdx.x) >> 6;
    const int lane = threadIdx.x & 63;
    if (w < KCODES) {
        float v0 = embed[(long)w * DIM + lane];
        float v1 = embed[(long)w * DIM + 64 + lane];
        float s  = v0 * v0 + v1 * v1;
        #pragma unroll
        for (int off = 32; off > 0; off >>= 1) s += __shfl_xor(s, off);
        if (lane == 0) hn[w] = 0.5f * s;
    }
}

// ---------------- Kernel 1: MFMA bf16x3 argmin + quantize gather ----------------
// score(p,c) = dot(x_p, e_c) - 0.5||e_c||^2, dot via hi*hi + hi*lo + lo*hi.
__global__ __launch_bounds__(NTHR, 2)
void argmin_kernel(const float* __restrict__ x, const float* __restrict__ embed,
                   const float* __restrict__ halfnorm, int* __restrict__ ind,
                   float* __restrict__ quant)
{
    __shared__ short es[TILE_C * DIM * 2];   // 64 KB, fragment-ordered {hi,lo}
    __shared__ int   bidx[BM];

    const int t     = threadIdx.x;
    const int lane  = t & 63;
    const int w     = t >> 6;          // wave 0..7, owns 32 points
    const int r16   = lane & 15;
    const int h4    = lane >> 4;       // k-group 0..3
    const int block = blockIdx.x;
    const long xbase = (long)block * BM * DIM;
    const int  wp    = w * 32;         // wave's local point base

    // ---- A fragments in registers: x rows -> hi/lo bf16 ----
    bf16x8 ahi[2][4], alo[2][4];
    #pragma unroll
    for (int ms = 0; ms < 2; ++ms) {
        const long prow = xbase + (long)(wp + ms * 16 + r16) * DIM;
        #pragma unroll
        for (int kk = 0; kk < 4; ++kk) {
            const float* src = x + prow + kk * 32 + h4 * 8;
            #pragma unroll
            for (int j = 0; j < 8; ++j) {
                float v  = src[j];
                short hi = f2bf(v);
                ahi[ms][kk][j] = hi;
                alo[ms][kk][j] = f2bf(v - bf2f(hi));
            }
        }
    }

    float bestv[8];
    int   besti[8];
    #pragma unroll
    for (int s = 0; s < 8; ++s) { bestv[s] = -1e30f; besti[s] = 0; }

    for (int tile = 0; tile < KCODES / TILE_C; ++tile) {
        __syncthreads();
        // ---- stage codebook tile, fragment-ordered: slot s = frag*64 + lane ----
        #pragma unroll
        for (int i = 0; i < 8; ++i) {
            int s  = i * NTHR + t;          // 0..4095
            int f  = s >> 6;                // frag id = h*32 + nt*4 + akk
            int l  = s & 63;
            int h  = f >> 5;
            int nt = (f >> 2) & 7;
            int akk = f & 3;
            int hg = l >> 4;
            int n  = l & 15;
            int c  = nt * 16 + n;
            int k8 = akk * 4 + hg;
            const float* src = embed + (long)(tile * TILE_C + c) * DIM + k8 * 8;
            bf16x8 val;
            #pragma unroll
            for (int j = 0; j < 8; ++j) {
                float v  = src[j];
                short hi = f2bf(v);
                val[j] = h ? f2bf(v - bf2f(hi)) : hi;
            }
            *(bf16x8*)(es + f * 512 + l * 8) = val;
        }
        __syncthreads();

        // ---- MFMA: C[nt][ms] over 12 k-steps (hi*hi, hi*lo, lo*hi) ----
        f32x4 C[8][2];
        #pragma unroll
        for (int nt = 0; nt < 8; ++nt)
            #pragma unroll
            for (int ms = 0; ms < 2; ++ms)
                C[nt][ms] = (f32x4){0.f, 0.f, 0.f, 0.f};

        #pragma unroll
        for (int kp = 0; kp < 12; ++kp) {
            const int akk = kp & 3;
            const int h   = (kp >= 4 && kp < 8) ? 1 : 0;   // B half: hi,lo,hi
            bf16x8 A0 = (kp < 8) ? ahi[0][akk] : alo[0][akk];
            bf16x8 A1 = (kp < 8) ? ahi[1][akk] : alo[1][akk];
            #pragma unroll
            for (int nt = 0; nt < 8; ++nt) {
                bf16x8 B = *(const bf16x8*)(es + (h * 32 + nt * 4 + akk) * 512 + lane * 8);
                C[nt][0] = __builtin_amdgcn_mfma_f32_16x16x32_bf16(A0, B, C[nt][0], 0, 0, 0);
                C[nt][1] = __builtin_amdgcn_mfma_f32_16x16x32_bf16(A1, B, C[nt][1], 0, 0, 0);
            }
        }

        // ---- scores + running argmax (codes ascending per lane) ----
        #pragma unroll
        for (int nt = 0; nt < 8; ++nt) {
            const int   c   = tile * TILE_C + nt * 16 + r16;
            const float hnv = halfnorm[c];
            #pragma unroll
            for (int ms = 0; ms < 2; ++ms)
                #pragma unroll
                for (int reg = 0; reg < 4; ++reg) {
                    float sc  = C[nt][ms][reg] - hnv;
                    int  slot = ms * 4 + reg;
                    if (sc > bestv[slot]) { bestv[slot] = sc; besti[slot] = c; }
                }
        }
    }

    // ---- butterfly reduce across the 16 columns (lane&15), tie -> smaller idx ----
    #pragma unroll
    for (int slot = 0; slot < 8; ++slot) {
        float v = bestv[slot];
        int   i = besti[slot];
        #pragma unroll
        for (int off = 1; off < 16; off <<= 1) {
            float ov = __shfl_xor(v, off);
            int   oi = __shfl_xor(i, off);
            if (ov > v || (ov == v && oi < i)) { v = ov; i = oi; }
        }
        bestv[slot] = v; besti[slot] = i;
    }
    if (r16 == 0) {
        #pragma unroll
        for (int slot = 0; slot < 8; ++slot) {
            int ms = slot >> 2, reg = slot & 3;
            int p  = wp + ms * 16 + h4 * 4 + reg;
            bidx[p] = besti[slot];
            ind[block * BM + p] = besti[slot];
        }
    }
    __syncthreads();

    // ---- quantize: lane-contiguous copy of embed[best] ----
    float4* dst = reinterpret_cast<float4*>(quant + xbase);
    #pragma unroll
    for (int i = 0; i < 16; ++i) {
        int idx = i * NTHR + t;
        int p   = idx >> 5;
        int q   = idx & 31;
        int c   = bidx[p];
        dst[idx] = reinterpret_cast<const float4*>(embed + (long)c * DIM)[q];
    }
}

// ---------------- Kernel 2a: partitioned code-centric segment sums ----------------
#define CPB   4
#define PPART 4
__global__ __launch_bounds__(256)
void segsum_part_kernel(const float* __restrict__ x, const int* __restrict__ ind,
                        float* __restrict__ partial, float* __restrict__ pcnt)
{
    __shared__ float wacc[4][CPB][DIM];
    __shared__ int   wcnt[4][CPB];

    const int t    = threadIdx.x;
    const int w    = t >> 6;
    const int lane = t & 63;
    const int cblk = blockIdx.x >> 2;   // 0..255 (4 codes each)
    const int part = blockIdx.x & 3;

    for (int i = t; i < 4 * CPB * DIM; i += 256) (&wacc[0][0][0])[i] = 0.f;
    __syncthreads();

    int cnt[CPB] = {0, 0, 0, 0};
    const int base = part * (NPTS / PPART);
    for (int k = 0; k < NPTS / PPART / 256; ++k) {
        const int i = base + k * 256 + t;
        const int v = ind[i];
        if (__ballot((v >> 2) == cblk)) {
            #pragma unroll
            for (int cc = 0; cc < CPB; ++cc) {
                unsigned long long m = __ballot(v == cblk * CPB + cc);
                cnt[cc] += (int)__popcll(m);
                while (m) {
                    int l = __ffsll((unsigned long long)m) - 1;
                    m &= m - 1;
                    long p = (long)base + k * 256 + w * 64 + l;
                    wacc[w][cc][lane]      += x[p * DIM + lane];
                    wacc[w][cc][lane + 64] += x[p * DIM + 64 + lane];
                }
            }
        }
    }
    if (lane == 0) {
        #pragma unroll
        for (int cc = 0; cc < CPB; ++cc) wcnt[w][cc] = cnt[cc];
    }
    __syncthreads();

    if (t < DIM) {
        #pragma unroll
        for (int cc = 0; cc < CPB; ++cc) {
            const int c = cblk * CPB + cc;
            partial[((long)part * KCODES + c) * DIM + t] =
                wacc[0][cc][t] + wacc[1][cc][t] + wacc[2][cc][t] + wacc[3][cc][t];
        }
    }
    if (t < CPB) {
        const int c = cblk * CPB + t;
        pcnt[part * KCODES + c] =
            (float)(wcnt[0][t] + wcnt[1][t] + wcnt[2][t] + wcnt[3][t]);
    }
}

// ---------------- Kernel 2b: combine partials + EMA epilogue ----------------
__global__ __launch_bounds__(256)
void combine_kernel(const float* __restrict__ partial, const float* __restrict__ pcnt,
                    const float* __restrict__ ema_embed, const float* __restrict__ ema_num,
                    float* __restrict__ embed_new, float* __restrict__ ema_embed_new,
                    float* __restrict__ ema_num_new)
{
    const int t   = threadIdx.x;
    const int blk = blockIdx.x;        // 256 blocks x 4 codes
    if (t < DIM) {
        #pragma unroll
        for (int cc = 0; cc < CPB; ++cc) {
            const int c = blk * CPB + cc;
            float s = 0.f, n = 0.f;
            #pragma unroll
            for (int p = 0; p < PPART; ++p) {
                s += partial[((long)p * KCODES + c) * DIM + t];
                n += pcnt[p * KCODES + c];
            }
            float en = ema_num[c] * 0.8f + 0.2f * n;
            float ee = ema_embed[(long)c * DIM + t] * 0.8f + 0.2f * s;
            ema_embed_new[(long)c * DIM + t] = ee;
            embed_new[(long)c * DIM + t]     = ee / en;
            if (t == 0) ema_num_new[c] = en;
        }
    }
}

extern "C" void kernel_launch(void* const* d_in, const int* in_sizes, int n_in,
                              void* d_out, int out_size, void* d_ws, size_t ws_size,
                              hipStream_t stream)
{
    const float* x         = (const float*)d_in[0];
    const float* embed     = (const float*)d_in[1];
    const float* ema_embed = (const float*)d_in[2];
    const float* ema_num   = (const float*)d_in[3];

    float* out0 = (float*)d_out;            // quantize      (16*4096*128)
    float* out1 = out0 + 8388608;           // embed_new     (1024*128)
    float* out2 = out1 + 131072;            // ema_embed_new (1024*128)
    float* out3 = out2 + 131072;            // ema_num_new   (1024)

    char* ws = (char*)d_ws;
    float* hn      = (float*)ws;                         // 4 KB
    int*   ind     = (int*)(ws + 4096);                  // 256 KB
    float* partial = (float*)(ws + 4096 + 262144);       // 2 MB (4 x 1024 x 128)
    float* pcnt    = (float*)(ws + 4096 + 262144 + 2097152); // 16 KB

    halfnorm_kernel<<<256, 256, 0, stream>>>(embed, hn);
    argmin_kernel<<<NPTS / BM, NTHR, 0, stream>>>(x, embed, hn, ind, out0);
    segsum_part_kernel<<<(KCODES / CPB) * PPART, 256, 0, stream>>>(x, ind, partial, pcnt);
    combine_kernel<<<KCODES / CPB, 256, 0, stream>>>(partial, pcnt, ema_embed, ema_num,
                                                     out1, out2, out3);
}

// Round 4
// 117.652 us; speedup vs baseline: 4.5877x; 1.6944x over previous
//
#include <hip/hip_runtime.h>

#define NPTS   65536
#define DIM    128
#define KCODES 1024
#define BM     128      // points per argmin block
#define TILE_C 128      // codes per LDS tile
#define NTHR   512

typedef short bf16x8 __attribute__((ext_vector_type(8)));
typedef float f32x4  __attribute__((ext_vector_type(4)));

__device__ __forceinline__ short f2bf(float f) {
    unsigned u = __builtin_bit_cast(unsigned, f);
    u = (u + 0x7fffu + ((u >> 16) & 1u)) >> 16;   // RNE
    return (short)u;
}
__device__ __forceinline__ float bf2f(short s) {
    unsigned u = ((unsigned)(unsigned short)s) << 16;
    return __builtin_bit_cast(float, u);
}
__device__ __forceinline__ void gload_lds16(const void* g, void* l) {
    __builtin_amdgcn_global_load_lds(
        (const __attribute__((address_space(1))) void*)g,
        (__attribute__((address_space(3))) void*)l, 16, 0, 0);
}

// ---------------- Kernel 0: halfnorm[c] = 0.5 * ||embed[c]||^2 (exact fp32) ----
__global__ __launch_bounds__(256)
void halfnorm_kernel(const float* __restrict__ embed, float* __restrict__ hn)
{
    const int w    = (blockIdx.x * blockDim.x + threadIdx.x) >> 6;
    const int lane = threadIdx.x & 63;
    if (w < KCODES) {
        float v0 = embed[(long)w * DIM + lane];
        float v1 = embed[(long)w * DIM + 64 + lane];
        float s  = v0 * v0 + v1 * v1;
        #pragma unroll
        for (int off = 32; off > 0; off >>= 1) s += __shfl_xor(s, off);
        if (lane == 0) hn[w] = 0.5f * s;
    }
}

// ---------------- Kernel P: pack codebook -> fragment-ordered bf16 hi/lo -------
// slot g: tc=g>>12, f=(g>>6)&63, l=g&63; f = h*32+nt*4+akk; l = hg*16+n
// value: half h of embed[tc*128+nt*16+n][akk*32+hg*8+j]
__global__ __launch_bounds__(256)
void pack_kernel(const float* __restrict__ embed, short* __restrict__ ebf)
{
    const int g   = blockIdx.x * 256 + threadIdx.x;   // 0..32767
    const int tc  = g >> 12;
    const int f   = (g >> 6) & 63;
    const int l   = g & 63;
    const int h   = f >> 5;
    const int nt  = (f >> 2) & 7;
    const int akk = f & 3;
    const int hg  = l >> 4;
    const int n   = l & 15;
    const int c   = tc * TILE_C + nt * 16 + n;
    const int d0  = akk * 32 + hg * 8;
    const float* src = embed + (long)c * DIM + d0;
    float4 v0 = *reinterpret_cast<const float4*>(src);
    float4 v1 = *reinterpret_cast<const float4*>(src + 4);
    float vv[8] = {v0.x, v0.y, v0.z, v0.w, v1.x, v1.y, v1.z, v1.w};
    bf16x8 out;
    #pragma unroll
    for (int j = 0; j < 8; ++j) {
        short hi = f2bf(vv[j]);
        out[j] = h ? f2bf(vv[j] - bf2f(hi)) : hi;
    }
    *reinterpret_cast<bf16x8*>(ebf + (long)g * 8) = out;
}

// ---------------- Kernel 1: MFMA bf16x3 argmin + quantize gather ----------------
__global__ __launch_bounds__(NTHR, 4)
void argmin_kernel(const float* __restrict__ x, const short* __restrict__ ebf,
                   const float* __restrict__ halfnorm, const float* __restrict__ embed,
                   int* __restrict__ ind, float* __restrict__ quant)
{
    __shared__ short es[64 * 512];      // 64 KB, fragment-ordered tile
    __shared__ float hn_lds[KCODES];    // 4 KB
    __shared__ int   bidx[BM];

    const int t    = threadIdx.x;
    const int lane = t & 63;
    const int w    = t >> 6;           // wave 0..7, owns 16 points
    const int r16  = lane & 15;
    const int h4   = lane >> 4;
    const long xbase = (long)blockIdx.x * BM * DIM;
    const int  wp    = w * 16;

    // ---- A fragments: x row (wp+r16), hi/lo bf16 ----
    bf16x8 ahi[4], alo[4];
    {
        const long prow = xbase + (long)(wp + r16) * DIM;
        #pragma unroll
        for (int kk = 0; kk < 4; ++kk) {
            const float* s = x + prow + kk * 32 + h4 * 8;
            float4 u0 = *reinterpret_cast<const float4*>(s);
            float4 u1 = *reinterpret_cast<const float4*>(s + 4);
            float vv[8] = {u0.x, u0.y, u0.z, u0.w, u1.x, u1.y, u1.z, u1.w};
            #pragma unroll
            for (int j = 0; j < 8; ++j) {
                short hi = f2bf(vv[j]);
                ahi[kk][j] = hi;
                alo[kk][j] = f2bf(vv[j] - bf2f(hi));
            }
        }
    }
    // ---- stage halfnorm into LDS ----
    if (t < 256) reinterpret_cast<float4*>(hn_lds)[t] =
                 reinterpret_cast<const float4*>(halfnorm)[t];

    float bestv[4];
    int   besti[4];
    #pragma unroll
    for (int s = 0; s < 4; ++s) { bestv[s] = -1e30f; besti[s] = 0; }

    for (int tile = 0; tile < KCODES / TILE_C; ++tile) {
        __syncthreads();   // prev tile's readers done (and hn/A staging on tile 0)
        // ---- async stage: wave w loads frags w*8..w*8+7, 1 KB each ----
        #pragma unroll
        for (int i = 0; i < 8; ++i) {
            const int f = w * 8 + i;
            gload_lds16(ebf + (long)tile * 32768 + f * 512 + lane * 8, es + f * 512);
        }
        __syncthreads();   // vmcnt(0) drain -> tile resident

        f32x4 C[8];
        #pragma unroll
        for (int nt = 0; nt < 8; ++nt) C[nt] = (f32x4){0.f, 0.f, 0.f, 0.f};

        #pragma unroll
        for (int akk = 0; akk < 4; ++akk) {
            #pragma unroll
            for (int nt = 0; nt < 8; ++nt) {
                bf16x8 Bh = *reinterpret_cast<const bf16x8*>(es + (nt * 4 + akk) * 512 + lane * 8);
                C[nt] = __builtin_amdgcn_mfma_f32_16x16x32_bf16(ahi[akk], Bh, C[nt], 0, 0, 0);
                C[nt] = __builtin_amdgcn_mfma_f32_16x16x32_bf16(alo[akk], Bh, C[nt], 0, 0, 0);
                bf16x8 Bl = *reinterpret_cast<const bf16x8*>(es + (32 + nt * 4 + akk) * 512 + lane * 8);
                C[nt] = __builtin_amdgcn_mfma_f32_16x16x32_bf16(ahi[akk], Bl, C[nt], 0, 0, 0);
            }
        }

        // ---- scores + running argmax (codes ascending per lane) ----
        #pragma unroll
        for (int nt = 0; nt < 8; ++nt) {
            const int   c   = tile * TILE_C + nt * 16 + r16;
            const float hnv = hn_lds[c];
            #pragma unroll
            for (int reg = 0; reg < 4; ++reg) {
                float sc = C[nt][reg] - hnv;
                if (sc > bestv[reg]) { bestv[reg] = sc; besti[reg] = c; }
            }
        }
    }

    // ---- butterfly reduce across 16 columns, tie -> smaller idx ----
    #pragma unroll
    for (int s = 0; s < 4; ++s) {
        float v = bestv[s];
        int   i = besti[s];
        #pragma unroll
        for (int off = 1; off < 16; off <<= 1) {
            float ov = __shfl_xor(v, off);
            int   oi = __shfl_xor(i, off);
            if (ov > v || (ov == v && oi < i)) { v = ov; i = oi; }
        }
        bestv[s] = v; besti[s] = i;
    }
    if (r16 == 0) {
        #pragma unroll
        for (int s = 0; s < 4; ++s) {
            int p = wp + h4 * 4 + s;      // row = h4*4 + reg
            bidx[p] = besti[s];
            ind[blockIdx.x * BM + p] = besti[s];
        }
    }
    __syncthreads();

    // ---- quantize: lane-contiguous gather-copy of embed[best] ----
    float4* dst = reinterpret_cast<float4*>(quant + xbase);
    #pragma unroll
    for (int i = 0; i < 8; ++i) {
        int idx = i * NTHR + t;          // 0..4095
        int p   = idx >> 5;
        int q   = idx & 31;
        int c   = bidx[p];
        dst[idx] = reinterpret_cast<const float4*>(embed + (long)c * DIM)[q];
    }
}

// ---------------- Kernel 2a: partitioned code-centric segment sums ----------------
#define CPB 4
__global__ __launch_bounds__(256)
void segsum_part_kernel(const float* __restrict__ x, const int* __restrict__ ind,
                        float* __restrict__ partial, float* __restrict__ pcnt,
                        int nchunk)
{
    __shared__ float wacc[4][CPB][DIM];
    __shared__ int   wcnt[4][CPB];

    const int t    = threadIdx.x;
    const int w    = t >> 6;
    const int lane = t & 63;
    const int cblk = blockIdx.x;        // 0..255 (4 codes each)
    const int part = blockIdx.y;

    for (int i = t; i < 4 * CPB * DIM; i += 256) (&wacc[0][0][0])[i] = 0.f;
    __syncthreads();

    int cnt[CPB] = {0, 0, 0, 0};
    const int base = part * nchunk * 256;
    for (int k = 0; k < nchunk; ++k) {
        const int i = base + k * 256 + t;
        const int v = ind[i];
        if (__ballot((v >> 2) == cblk)) {
            #pragma unroll
            for (int cc = 0; cc < CPB; ++cc) {
                unsigned long long m = __ballot(v == cblk * CPB + cc);
                cnt[cc] += (int)__popcll(m);
                while (m) {
                    int l = __ffsll((unsigned long long)m) - 1;
                    m &= m - 1;
                    long p = (long)base + k * 256 + w * 64 + l;
                    wacc[w][cc][lane]      += x[p * DIM + lane];
                    wacc[w][cc][lane + 64] += x[p * DIM + 64 + lane];
                }
            }
        }
    }
    if (lane == 0) {
        #pragma unroll
        for (int cc = 0; cc < CPB; ++cc) wcnt[w][cc] = cnt[cc];
    }
    __syncthreads();

    if (t < DIM) {
        #pragma unroll
        for (int cc = 0; cc < CPB; ++cc) {
            const int c = cblk * CPB + cc;
            partial[((long)part * KCODES + c) * DIM + t] =
                wacc[0][cc][t] + wacc[1][cc][t] + wacc[2][cc][t] + wacc[3][cc][t];
        }
    }
    if (t < CPB) {
        const int c = cblk * CPB + t;
        pcnt[(long)part * KCODES + c] =
            (float)(wcnt[0][t] + wcnt[1][t] + wcnt[2][t] + wcnt[3][t]);
    }
}

// ---------------- Kernel 2b: combine partials + EMA epilogue ----------------
__global__ __launch_bounds__(256)
void combine_kernel(const float* __restrict__ partial, const float* __restrict__ pcnt,
                    const float* __restrict__ ema_embed, const float* __restrict__ ema_num,
                    float* __restrict__ embed_new, float* __restrict__ ema_embed_new,
                    float* __restrict__ ema_num_new, int npart)
{
    const int t   = threadIdx.x;
    const int blk = blockIdx.x;
    if (t < DIM) {
        #pragma unroll
        for (int cc = 0; cc < CPB; ++cc) {
            const int c = blk * CPB + cc;
            float s = 0.f, n = 0.f;
            for (int p = 0; p < npart; ++p) {
                s += partial[((long)p * KCODES + c) * DIM + t];
                n += pcnt[(long)p * KCODES + c];
            }
            float en = ema_num[c] * 0.8f + 0.2f * n;
            float ee = ema_embed[(long)c * DIM + t] * 0.8f + 0.2f * s;
            ema_embed_new[(long)c * DIM + t] = ee;
            embed_new[(long)c * DIM + t]     = ee / en;
            if (t == 0) ema_num_new[c] = en;
        }
    }
}

extern "C" void kernel_launch(void* const* d_in, const int* in_sizes, int n_in,
                              void* d_out, int out_size, void* d_ws, size_t ws_size,
                              hipStream_t stream)
{
    const float* x         = (const float*)d_in[0];
    const float* embed     = (const float*)d_in[1];
    const float* ema_embed = (const float*)d_in[2];
    const float* ema_num   = (const float*)d_in[3];

    float* out0 = (float*)d_out;            // quantize      (16*4096*128)
    float* out1 = out0 + 8388608;           // embed_new     (1024*128)
    float* out2 = out1 + 131072;            // ema_embed_new (1024*128)
    float* out3 = out2 + 131072;            // ema_num_new   (1024)

    // ws layout: [hn 4K][ind 256K][ebf 512K / partial (overlay, ebf dead by then)][pcnt]
    char*  ws      = (char*)d_ws;
    float* hn      = (float*)ws;                       // 4 KB
    int*   ind     = (int*)(ws + 4096);                // 256 KB
    short* ebf     = (short*)(ws + 266240);            // 512 KB
    float* partial = (float*)(ws + 266240);            // npart * 512 KB (reuses ebf)
    const int npart = (ws_size >= (size_t)(266240 + 8 * 524288 + 32768)) ? 8 : 4;
    float* pcnt    = (float*)(ws + 266240 + (size_t)npart * 524288);
    const int nchunk = NPTS / npart / 256;

    halfnorm_kernel<<<256, 256, 0, stream>>>(embed, hn);
    pack_kernel<<<128, 256, 0, stream>>>(embed, ebf);
    argmin_kernel<<<NPTS / BM, NTHR, 0, stream>>>(x, ebf, hn, embed, ind, out0);
    segsum_part_kernel<<<dim3(KCODES / CPB, npart), 256, 0, stream>>>(x, ind, partial, pcnt, nchunk);
    combine_kernel<<<KCODES / CPB, 256, 0, stream>>>(partial, pcnt, ema_embed, ema_num,
                                                     out1, out2, out3, npart);
}